// Round 3
// baseline (248.243 us; speedup 1.0000x reference)
//
#include <hip/hip_runtime.h>
#include <hip/hip_bf16.h>

// PyramidLevel1Block: out[b,m,:] = relu(BN(W^T concat(pre_x[b,:,m], cur_x[b,:,idx]) + b))
// B=4, M=65536, N=16384, C_pre=64, C_cur=128, D=128.
//
// Key restructure: the gathered half of the GEMM depends only on (b, idx) and there
// are only B*N = 65536 distinct gather targets vs B*M = 262144 rows. So:
//   K1: Z[b,n,:] = W_cur^T cur_x[b,:,n]  (65536x128x128 GEMM, bf16 out, 16.8 MB -> d_ws)
//   K2: out = relu(scale*(W_pre^T pre_x[b,:,m] + Z[b,idx[b,m],:]) + shift)
// K2 keeps only K=64 of MFMA work (16 MFMAs / 64-row tile) + a 256 B/row Z gather
// that stays L3-resident.

typedef short bhalf8 __attribute__((ext_vector_type(8)));
typedef float f32x4 __attribute__((ext_vector_type(4)));
typedef unsigned int u32x4 __attribute__((ext_vector_type(4)));

__device__ __forceinline__ short f2bf(float f) {
  // round-to-nearest-even float -> bf16 (finite inputs only)
  unsigned int u = __float_as_uint(f);
  unsigned int r = (u + 0x7fffu + ((u >> 16) & 1u)) >> 16;
  return (short)r;
}
__device__ __forceinline__ float bf2f(short s) {
  return __uint_as_float(((unsigned int)(unsigned short)s) << 16);
}

#define ZST 136  // LDS row stride (shorts) for 128-col tiles: 272 B, 16B-aligned, 68 dw %32=4
#define PST 72   // LDS row stride (shorts) for 64-col pre tile: 144 B, 16B-aligned

// ---------------- K1: Z[b,n,d] = sum_c cur_x[b,c,n] * w[64+c][d], bf16 out ---------
__global__ __launch_bounds__(256, 4) void cur_gemm(const float* __restrict__ cur,
                                                   const float* __restrict__ w,
                                                   short* __restrict__ Z) {
  __shared__ short lds[64 * ZST];  // first: A-tile [64 n][128 c]; then: D-tile [64 n][128 d]
  const int tid = threadIdx.x;
  const int lane = tid & 63;
  const int wv = tid >> 6;  // wave -> cols [32wv, 32wv+32)
  const int c = lane & 15;
  const int g = lane >> 4;
  const int r0 = blockIdx.x << 6;  // flat row = b*16384 + n
  const int b = r0 >> 14;
  const int n0 = r0 & 16383;
  const float* src = cur + (size_t)b * 128 * 16384 + n0;

  // W fragments (cur rows 64..191): bw[s][ct][j] = w[(64+32s+8g+j)*128 + col]
  bhalf8 bw[4][2];
#pragma unroll
  for (int s = 0; s < 4; ++s)
#pragma unroll
    for (int ct = 0; ct < 2; ++ct) {
      const int col = 32 * wv + 16 * ct + c;
#pragma unroll
      for (int j = 0; j < 8; ++j)
        bw[s][ct][j] = f2bf(w[(64 + 32 * s + 8 * g + j) * 128 + col]);
    }

  // stage cur tile: 128 c x 64 n, coalesced f32x4 along n, transpose into LDS bf16
#pragma unroll
  for (int it = 0; it < 8; ++it) {
    int v = it * 256 + tid;
    int cc = v >> 4;         // 0..127 channel
    int nq = (v & 15) << 2;  // n quad
    f32x4 f = __builtin_nontemporal_load(
        reinterpret_cast<const f32x4*>(&src[(size_t)cc * 16384 + nq]));
#pragma unroll
    for (int k = 0; k < 4; ++k) lds[(nq + k) * ZST + cc] = f2bf(f[k]);
  }
  __syncthreads();

  // MFMA: all row-tiles, accs held in registers
  f32x4 acc[4][2];
#pragma unroll
  for (int rt = 0; rt < 4; ++rt) {
    bhalf8 a[4];
#pragma unroll
    for (int s = 0; s < 4; ++s)
      a[s] = *reinterpret_cast<const bhalf8*>(&lds[(16 * rt + c) * ZST + 32 * s + 8 * g]);
    acc[rt][0] = (f32x4){0.f, 0.f, 0.f, 0.f};
    acc[rt][1] = (f32x4){0.f, 0.f, 0.f, 0.f};
#pragma unroll
    for (int s = 0; s < 4; ++s) {
      acc[rt][0] = __builtin_amdgcn_mfma_f32_16x16x32_bf16(a[s], bw[s][0], acc[rt][0], 0, 0, 0);
      acc[rt][1] = __builtin_amdgcn_mfma_f32_16x16x32_bf16(a[s], bw[s][1], acc[rt][1], 0, 0, 0);
    }
  }
  __syncthreads();
  // bounce D through LDS for coalesced bf16 stores
#pragma unroll
  for (int rt = 0; rt < 4; ++rt)
#pragma unroll
    for (int ct = 0; ct < 2; ++ct)
#pragma unroll
      for (int i = 0; i < 4; ++i)
        lds[(16 * rt + 4 * g + i) * ZST + 32 * wv + 16 * ct + c] = f2bf(acc[rt][ct][i]);
  __syncthreads();
  short* dst = Z + (size_t)r0 * 128;
  const int row = tid >> 2, q = tid & 3;  // 64 B per thread, fully coalesced
#pragma unroll
  for (int u = 0; u < 4; ++u) {
    bhalf8 pk = *reinterpret_cast<const bhalf8*>(&lds[row * ZST + q * 32 + 8 * u]);
    __builtin_nontemporal_store(pk, reinterpret_cast<bhalf8*>(&dst[(size_t)row * 128 + q * 32 + 8 * u]));
  }
}

// ---------------- K2: fused pre-GEMM + Z gather + BN + ReLU ------------------------
#define NBLK 2048  // 4096 row-groups of 64, 2 per block

__global__ __launch_bounds__(256, 4) void fused_main(
    const float* __restrict__ pre_x,  // (4, 64, 65536)
    const int* __restrict__ up_idx,   // (4, 65536)
    const float* __restrict__ w,      // (192, 128)
    const float* __restrict__ bias, const float* __restrict__ gamma,
    const float* __restrict__ beta, const float* __restrict__ rmean,
    const float* __restrict__ rvar,
    const short* __restrict__ Z,  // (4, 16384, 128) bf16
    float* __restrict__ out)      // (4, 65536, 128) f32
{
  __shared__ short pre_lds[64 * PST];  // [64 m][64 k] bf16
  __shared__ short z_lds[64 * ZST];    // [64 m][128 d] bf16 gathered rows
  const int tid = threadIdx.x;
  const int lane = tid & 63;
  const int wv = tid >> 6;
  const int c = lane & 15;
  const int g = lane >> 4;

  // W fragments (pre rows 0..63)
  bhalf8 bw[2][2];
#pragma unroll
  for (int s = 0; s < 2; ++s)
#pragma unroll
    for (int ct = 0; ct < 2; ++ct) {
      const int col = 32 * wv + 16 * ct + c;
#pragma unroll
      for (int j = 0; j < 8; ++j)
        bw[s][ct][j] = f2bf(w[(32 * s + 8 * g + j) * 128 + col]);
    }
  // fold bias + BN: y = (dot + z)*scale + shift
  float scale[2], shift[2];
#pragma unroll
  for (int ct = 0; ct < 2; ++ct) {
    const int d = 32 * wv + 16 * ct + c;
    float sc = gamma[d] * rsqrtf(rvar[d] + 1e-5f);
    scale[ct] = sc;
    shift[ct] = (bias[d] - rmean[d]) * sc + beta[d];
  }

  for (int t = 0; t < 2; ++t) {
    const long rg = blockIdx.x + (long)t * NBLK;
    const long r0 = rg << 6;
    const int b = (int)(r0 >> 16);
    const int m0 = (int)(r0 & 65535);
    if (t) __syncthreads();

    // stage pre_x: 64 c x 64 m, coalesced f32x4 along m, transpose into LDS bf16
    {
      const float* pb = pre_x + (size_t)b * 64 * 65536 + m0;
#pragma unroll
      for (int it = 0; it < 4; ++it) {
        int v = it * 256 + tid;
        int cc = v >> 4;
        int mq = (v & 15) << 2;
        f32x4 f = __builtin_nontemporal_load(
            reinterpret_cast<const f32x4*>(&pb[(size_t)cc * 65536 + mq]));
#pragma unroll
        for (int k = 0; k < 4; ++k) pre_lds[(mq + k) * PST + cc] = f2bf(f[k]);
      }
    }
    // stage gathered Z rows: 256 B contiguous per row
    {
#pragma unroll
      for (int it = 0; it < 4; ++it) {
        int mm = it * 16 + (tid >> 4);
        int seg = tid & 15;
        int n = up_idx[r0 + mm];
        const short* srcp = Z + ((size_t)b * 16384 + n) * 128 + seg * 8;
        *reinterpret_cast<u32x4*>(&z_lds[mm * ZST + seg * 8]) =
            *reinterpret_cast<const u32x4*>(srcp);
      }
    }
    __syncthreads();

#pragma unroll
    for (int rt = 0; rt < 4; ++rt) {
      bhalf8 a[2];
#pragma unroll
      for (int s = 0; s < 2; ++s)
        a[s] = *reinterpret_cast<const bhalf8*>(
            &pre_lds[(16 * rt + c) * PST + 32 * s + 8 * g]);
      f32x4 acc0 = {0.f, 0.f, 0.f, 0.f};
      f32x4 acc1 = {0.f, 0.f, 0.f, 0.f};
#pragma unroll
      for (int s = 0; s < 2; ++s) {
        acc0 = __builtin_amdgcn_mfma_f32_16x16x32_bf16(a[s], bw[s][0], acc0, 0, 0, 0);
        acc1 = __builtin_amdgcn_mfma_f32_16x16x32_bf16(a[s], bw[s][1], acc1, 0, 0, 0);
      }
      // epilogue: row = 16rt+4g+i, cols 32wv+{c, 16+c}; add gathered Z, BN, ReLU
      float* ob = out + (size_t)(r0 + 16 * rt + 4 * g) * 128 + 32 * wv;
#pragma unroll
      for (int i = 0; i < 4; ++i) {
        const short* zr = &z_lds[(16 * rt + 4 * g + i) * ZST + 32 * wv];
        float z0 = bf2f(zr[c]);
        float z1 = bf2f(zr[16 + c]);
        float v0 = fmaxf((acc0[i] + z0) * scale[0] + shift[0], 0.f);
        float v1 = fmaxf((acc1[i] + z1) * scale[1] + shift[1], 0.f);
        __builtin_nontemporal_store(v0, ob + (size_t)i * 128 + c);
        __builtin_nontemporal_store(v1, ob + (size_t)i * 128 + 16 + c);
      }
    }
  }
}

extern "C" void kernel_launch(void* const* d_in, const int* in_sizes, int n_in,
                              void* d_out, int out_size, void* d_ws, size_t ws_size,
                              hipStream_t stream) {
  const float* pre_x = (const float*)d_in[0];
  const float* cur_x = (const float*)d_in[1];
  const int* up_idx = (const int*)d_in[2];
  const float* w = (const float*)d_in[3];
  const float* bias = (const float*)d_in[4];
  const float* gamma = (const float*)d_in[5];
  const float* beta = (const float*)d_in[6];
  const float* rmean = (const float*)d_in[7];
  const float* rvar = (const float*)d_in[8];
  float* out = (float*)d_out;
  short* Z = (short*)d_ws;  // (4, 16384, 128) bf16 = 16.8 MB

  hipLaunchKernelGGL(cur_gemm, dim3(1024), dim3(256), 0, stream, cur_x, w, Z);
  hipLaunchKernelGGL(fused_main, dim3(NBLK), dim3(256), 0, stream, pre_x, up_idx, w,
                     bias, gamma, beta, rmean, rvar, Z, out);
}